// Round 1
// baseline (293.928 us; speedup 1.0000x reference)
//
#include <hip/hip_runtime.h>

#define N_NODES 50000
#define N_EDGES 1600000
#define DIM 128
#define M_PAD 50048    // 782 * 64
#define NBKT 196       // buckets = dst >> 8
#define CHUNK 6250     // edges per build block
#define BB 256         // build blocks (BB * CHUNK == N_EDGES)

// ---------------- workspace layout (bytes) ----------------
// C layout per node: 1024 B = [Q: 128 fp32 | u32 0..127][K: 128 fp8 | u32 128..159]
//                             [V: 128 bf16 | u32 160..223][pad u32 224..255]
#define OFF_WCATB  0UL                    // 384*128*2   = 98304
#define OFF_BCAT   98304UL                // 384*4       = 1536
#define OFF_XB     99840UL                // 50048*128*2 = 12812288
#define OFF_C      12912128UL             // 50000*1024  = 51200000
#define OFF_SRC    64112128UL             // 1600000*2   = 3200000   (csr src ids, u16)
#define OFF_BKD    67312128UL             // 1600000*4   = 6400000   (bucketed (dloc<<16)|src)
#define OFF_CNT    73712128UL             // 196*256*4   = 200704    (per-(bucket,block) counts/offsets)
#define OFF_BSUM   73912832UL             // 196*4
#define OFF_BOFF   73913664UL             // 197*4       (bucket offsets)
#define OFF_RS     73914496UL             // 50001*4
#define OFF_AGG    74114560UL             // 50000*128*4 = 25600000  -> total ~99.7 MB

typedef __attribute__((ext_vector_type(8))) short short8;    // 8 bf16
typedef __attribute__((ext_vector_type(4))) float floatx4;   // MFMA acc
typedef __attribute__((ext_vector_type(2))) float fx2;       // packed fp8 cvt result

__device__ __forceinline__ unsigned bf16r(float f) {   // fp32 -> bf16 bits, RNE
    unsigned u = __float_as_uint(f);
    return (u + 0x7fffu + ((u >> 16) & 1u)) >> 16;
}
__device__ __forceinline__ unsigned pack2(float a, float b) {
    return bf16r(a) | (bf16r(b) << 16);
}
__device__ __forceinline__ float blo(unsigned v) { return __uint_as_float(v << 16); }
__device__ __forceinline__ float bhi(unsigned v) { return __uint_as_float(v & 0xffff0000u); }

// ---- D1: coarse bucket hist (LDS) | x->bf16 cvt | weight prep ----
#define CVT_NB 6250
#define PREPW_NB 192
#define PREP_GRID (BB + CVT_NB + PREPW_NB)   // 6698
__global__ __launch_bounds__(256) void k_prep(const float* __restrict__ x,
                                              unsigned short* __restrict__ xb,
                                              const float* __restrict__ Wq, const float* __restrict__ bq,
                                              const float* __restrict__ Wk, const float* __restrict__ bk,
                                              const float* __restrict__ Wv, const float* __restrict__ bv,
                                              unsigned short* __restrict__ Wcatb,
                                              float* __restrict__ bcat,
                                              const int* __restrict__ dstA,
                                              int* __restrict__ cnt) {
    __shared__ int h[NBKT];
    int bx = blockIdx.x, t = threadIdx.x;
    if (bx < BB) {                       // coarse hist: 196 LDS bins
        if (t < NBKT) h[t] = 0;
        __syncthreads();
        int base = bx * CHUNK;
        for (int i = t; i < CHUNK; i += 256)
            atomicAdd(&h[dstA[base + i] >> 8], 1);
        __syncthreads();
        if (t < NBKT) cnt[t * BB + bx] = h[t];
    } else if (bx < BB + CVT_NB) {       // cvt: one float4 per thread
        int i = (bx - BB) * 256 + t;
        if (i < N_NODES * DIM / 4) {
            float4 f = ((const float4*)x)[i];
            ushort4 o;
            o.x = (unsigned short)bf16r(f.x); o.y = (unsigned short)bf16r(f.y);
            o.z = (unsigned short)bf16r(f.z); o.w = (unsigned short)bf16r(f.w);
            ((ushort4*)xb)[i] = o;
        }
    } else {                             // weight prep
        int i = (bx - BB - CVT_NB) * 256 + t;
        if (i < 3 * DIM * DIM) {
            int ro = i >> 7, col = i & 127;
            const float* W = (ro < 128) ? Wq : (ro < 256) ? Wk : Wv;
            Wcatb[i] = (unsigned short)bf16r(W[(ro & 127) * DIM + col]);
        }
        if (i < 3 * DIM) {
            const float* b = (i < 128) ? bq : (i < 256) ? bk : bv;
            bcat[i] = b[i & 127];
        }
    }
}

// ---- tiny scans over the 196x256 count matrix ----
__global__ __launch_bounds__(256) void k_b2a(const int* __restrict__ cnt, int* __restrict__ bsum) {
    __shared__ int red[256];
    int t = threadIdx.x;
    red[t] = cnt[blockIdx.x * BB + t];
    __syncthreads();
    for (int off = 128; off > 0; off >>= 1) {
        if (t < off) red[t] += red[t + off];
        __syncthreads();
    }
    if (t == 0) bsum[blockIdx.x] = red[0];
}
__global__ __launch_bounds__(256) void k_b2b(const int* __restrict__ bsum, int* __restrict__ bktoff) {
    __shared__ int s[256];
    int t = threadIdx.x;
    int v = (t < NBKT) ? bsum[t] : 0;
    s[t] = v;
    __syncthreads();
    for (int off = 1; off < 256; off <<= 1) {
        int u = (t >= off) ? s[t - off] : 0;
        __syncthreads();
        s[t] += u;
        __syncthreads();
    }
    if (t < NBKT) bktoff[t] = s[t] - v;
    if (t == NBKT - 1) bktoff[NBKT] = s[t];
}
__global__ __launch_bounds__(256) void k_b2c(int* __restrict__ cnt, const int* __restrict__ bktoff) {
    __shared__ int s[256];
    int t = threadIdx.x;
    int v = cnt[blockIdx.x * BB + t];
    s[t] = v;
    __syncthreads();
    for (int off = 1; off < 256; off <<= 1) {
        int u = (t >= off) ? s[t - off] : 0;
        __syncthreads();
        s[t] += u;
        __syncthreads();
    }
    cnt[blockIdx.x * BB + t] = bktoff[blockIdx.x] + s[t] - v;   // absolute offset
}

// ---- D3: QKV MFMA GEMM interleaved 18:1 with bucket scatter (no global atomics) ----
#define GQ_MB (M_PAD / 64)          // 782
#define GQ_BLOCKS (GQ_MB * 6)       // 4692
#define GB3_GRPS 261
#define GB3_GRID (GB3_GRPS * 19)    // 4959
__global__ __launch_bounds__(256) void k_gemmqkv_b3(const unsigned short* __restrict__ xb,
                                                    const unsigned short* __restrict__ Wb,
                                                    const float* __restrict__ bias,
                                                    unsigned* __restrict__ Cu, int M,
                                                    const int* __restrict__ srcA,
                                                    const int* __restrict__ dstA,
                                                    const int* __restrict__ cnt,
                                                    unsigned* __restrict__ bucketed) {
    __shared__ __align__(16) unsigned short As[64][136];
    __shared__ __align__(16) unsigned short Bs[64][136];
    __shared__ int cur[NBKT];
    const int grp = blockIdx.x / 19, r = blockIdx.x % 19;
    const int t = threadIdx.x;
    if (r == 18) {                      // bucket scatter block
        if (grp < BB) {
            if (t < NBKT) cur[t] = cnt[t * BB + grp];
            __syncthreads();
            int base = grp * CHUNK;
            for (int i = t; i < CHUNK; i += 256) {
                int e = base + i;
                int d = dstA[e];
                int p = atomicAdd(&cur[d >> 8], 1);       // LDS
                bucketed[p] = (unsigned)srcA[e] | ((unsigned)(d & 255) << 16);
            }
        }
        return;
    }
    const int g = grp * 18 + r;
    if (g >= GQ_BLOCKS) return;
    const int m0 = (g % GQ_MB) * 64, n0 = (g / GQ_MB) * 64;
    {
        int row = t >> 2, ch = t & 3;
        const uint4* xrow = (const uint4*)(xb + (long)(m0 + row) * 128);
        const uint4* wrow = (const uint4*)(Wb + (long)(n0 + row) * 128);
#pragma unroll
        for (int j = 0; j < 4; ++j) {
            *(uint4*)&As[row][(ch + 4 * j) * 8] = xrow[ch + 4 * j];
            *(uint4*)&Bs[row][(ch + 4 * j) * 8] = wrow[ch + 4 * j];
        }
    }
    __syncthreads();
    const int w = t >> 6, lane = t & 63;
    const int quad = lane >> 4, c = lane & 15;
    floatx4 acc[4] = {{0.f,0.f,0.f,0.f},{0.f,0.f,0.f,0.f},{0.f,0.f,0.f,0.f},{0.f,0.f,0.f,0.f}};
#pragma unroll
    for (int ks = 0; ks < 4; ++ks) {
        short8 a = *(const short8*)&As[w * 16 + c][ks * 32 + quad * 8];
#pragma unroll
        for (int nt = 0; nt < 4; ++nt) {
            short8 b = *(const short8*)&Bs[nt * 16 + c][ks * 32 + quad * 8];
            acc[nt] = __builtin_amdgcn_mfma_f32_16x16x32_bf16(a, b, acc[nt], 0, 0, 0);
        }
    }
#pragma unroll
    for (int nt = 0; nt < 4; ++nt) {
        int gn = n0 + nt * 16 + c;
        float bv = bias[gn];
        int slice = gn >> 7;           // 0=Q 1=K(fp8) 2=V(bf16)
        int cs = gn & 127;
#pragma unroll
        for (int i = 0; i < 4; ++i) {
            int gm = m0 + w * 16 + quad * 4 + i;
            float o = acc[nt][i] + bv;
            float f1 = __shfl_xor(o, 1);
            float f2 = __shfl_xor(o, 2);
            float f3 = __shfl_xor(o, 3);
            if (gm < M) {
                unsigned* crow = Cu + (long)gm * 256;
                if (slice == 0) {
                    ((float*)crow)[cs] = o;
                } else if (slice == 1) {
                    if ((c & 3) == 0) {
                        int pk = __builtin_amdgcn_cvt_pk_fp8_f32(o, f1, 0, false);
                        pk = __builtin_amdgcn_cvt_pk_fp8_f32(f2, f3, pk, true);
                        crow[128 + (cs >> 2)] = (unsigned)pk;
                    }
                } else {
                    if ((c & 1) == 0) crow[160 + (cs >> 1)] = pack2(o, f1);
                }
            }
        }
    }
}

// ---- D4: per-bucket fine sort -> csr_src + row_start (all LDS atomics) ----
__global__ __launch_bounds__(256) void k_b4(const unsigned* __restrict__ bucketed,
                                            const int* __restrict__ bktoff,
                                            unsigned short* __restrict__ csr_src,
                                            int* __restrict__ row_start) {
    __shared__ int h[256], s[256], cur[256];
    int b = blockIdx.x, t = threadIdx.x;
    int base = bktoff[b], end = bktoff[b + 1];
    h[t] = 0;
    __syncthreads();
    for (int p = base + t; p < end; p += 256)
        atomicAdd(&h[bucketed[p] >> 16], 1);
    __syncthreads();
    int v = h[t];
    s[t] = v;
    __syncthreads();
    for (int off = 1; off < 256; off <<= 1) {
        int u = (t >= off) ? s[t - off] : 0;
        __syncthreads();
        s[t] += u;
        __syncthreads();
    }
    int start = base + s[t] - v;
    int d = b * 256 + t;
    if (d < N_NODES) row_start[d] = start;
    if (d == N_NODES - 1) row_start[N_NODES] = N_EDGES;
    cur[t] = start;
    __syncthreads();
    for (int p = base + t; p < end; p += 256) {
        unsigned u = bucketed[p];
        int q = atomicAdd(&cur[u >> 16], 1);              // LDS
        csr_src[q] = (unsigned short)(u & 0xffffu);
    }
}

// ---- fused scores+softmax+aggregate, half-wave layout, no max shift ----
// v2: software-pipelined gathers. The 32-VGPR baseline serialized the 12
// gather loads per 8-edge block behind waitcnts (latency-bound: VALUBusy 56%,
// hbm 45%, nothing saturated). Two-phase (even/odd register set) pipeline:
// ids for block b+2 and K/V for block b+1 are issued around block b's
// compute, so every gather has ~1 compute-block (~200 cy) of latency cover.
// No register-rotation moves (those would force early waits).
__global__ __launch_bounds__(256) void k_attn(const unsigned* __restrict__ Cu,
                                              const int* __restrict__ row_start,
                                              const unsigned short* __restrict__ csr_src,
                                              float* __restrict__ agg) {
    int d = blockIdx.x * 4 + (threadIdx.x >> 6);
    int lane = threadIdx.x & 63;
    if (d >= N_NODES) return;
    const int half = lane >> 5, sl = lane & 31;
    const float scale = 0.17677669529663687f;   // 1/sqrt(32), folded into q
    float4 q4 = *(const float4*)((const float*)(Cu + (long)d * 256) + 4 * sl);
    q4.x *= scale; q4.y *= scale; q4.z *= scale; q4.w *= scale;
    int s0 = row_start[d], s1 = row_start[d + 1];
    float lsum = 0.f, a0 = 0.f, a1 = 0.f, a2 = 0.f, a3 = 0.f;

#define LOADIDS(P, j0, j1, j2, j3)                       \
    {                                                    \
        int _b = (P) + half * 4;                         \
        j0 = csr_src[_b + 0];                            \
        j1 = csr_src[_b + 1];                            \
        j2 = csr_src[_b + 2];                            \
        j3 = csr_src[_b + 3];                            \
    }
#define ISSUEKV(j0, j1, j2, j3, ka, kb, kc, kd, va, vb, vc, vd) \
    {                                                           \
        const unsigned* _r0 = Cu + (long)(j0) * 256;            \
        const unsigned* _r1 = Cu + (long)(j1) * 256;            \
        const unsigned* _r2 = Cu + (long)(j2) * 256;            \
        const unsigned* _r3 = Cu + (long)(j3) * 256;            \
        ka = _r0[128 + sl];                                     \
        kb = _r1[128 + sl];                                     \
        kc = _r2[128 + sl];                                     \
        kd = _r3[128 + sl];                                     \
        va = *(const uint2*)(_r0 + 160 + 2 * sl);               \
        vb = *(const uint2*)(_r1 + 160 + 2 * sl);               \
        vc = *(const uint2*)(_r2 + 160 + 2 * sl);               \
        vd = *(const uint2*)(_r3 + 160 + 2 * sl);               \
    }
#define COMPUTE(ka, kb, kc, kd, va, vb, vc, vd)                                        \
    {                                                                                  \
        fx2 a01 = __builtin_amdgcn_cvt_pk_f32_fp8((int)(ka), false);                   \
        fx2 a23 = __builtin_amdgcn_cvt_pk_f32_fp8((int)(ka), true);                    \
        fx2 b01 = __builtin_amdgcn_cvt_pk_f32_fp8((int)(kb), false);                   \
        fx2 b23 = __builtin_amdgcn_cvt_pk_f32_fp8((int)(kb), true);                    \
        fx2 c01 = __builtin_amdgcn_cvt_pk_f32_fp8((int)(kc), false);                   \
        fx2 c23 = __builtin_amdgcn_cvt_pk_f32_fp8((int)(kc), true);                    \
        fx2 d01 = __builtin_amdgcn_cvt_pk_f32_fp8((int)(kd), false);                   \
        fx2 d23 = __builtin_amdgcn_cvt_pk_f32_fp8((int)(kd), true);                    \
        float pa = q4.x * a01.x + q4.y * a01.y + q4.z * a23.x + q4.w * a23.y;          \
        float pb = q4.x * b01.x + q4.y * b01.y + q4.z * b23.x + q4.w * b23.y;          \
        float pc = q4.x * c01.x + q4.y * c01.y + q4.z * c23.x + q4.w * c23.y;          \
        float pd = q4.x * d01.x + q4.y * d01.y + q4.z * d23.x + q4.w * d23.y;          \
        pa += __shfl_xor(pa, 1); pa += __shfl_xor(pa, 2); pa += __shfl_xor(pa, 4);     \
        pb += __shfl_xor(pb, 1); pb += __shfl_xor(pb, 2); pb += __shfl_xor(pb, 4);     \
        pc += __shfl_xor(pc, 1); pc += __shfl_xor(pc, 2); pc += __shfl_xor(pc, 4);     \
        pd += __shfl_xor(pd, 1); pd += __shfl_xor(pd, 2); pd += __shfl_xor(pd, 4);     \
        float wa = __expf(pa), wb = __expf(pb), wc = __expf(pc), wd = __expf(pd);      \
        lsum += (wa + wb) + (wc + wd);                                                 \
        a0 += wa * blo((va).x) + wb * blo((vb).x) + wc * blo((vc).x) + wd * blo((vd).x); \
        a1 += wa * bhi((va).x) + wb * bhi((vb).x) + wc * bhi((vc).x) + wd * bhi((vd).x); \
        a2 += wa * blo((va).y) + wb * blo((vb).y) + wc * blo((vc).y) + wd * blo((vd).y); \
        a3 += wa * bhi((va).y) + wb * bhi((vb).y) + wc * bhi((vc).y) + wd * bhi((vd).y); \
    }

    int nb = (s1 - s0) >> 3;   // full 8-edge blocks (4 per half-wave)
    int p = s0;

    int iA0, iA1, iA2, iA3, iB0, iB1, iB2, iB3;
    unsigned kA0, kA1, kA2, kA3, kB0, kB1, kB2, kB3;
    uint2 vA0, vA1, vA2, vA3, vB0, vB1, vB2, vB3;

    if (nb > 0) {                       // prologue: block0 ids+KV, block1 ids
        LOADIDS(p, iA0, iA1, iA2, iA3);
        ISSUEKV(iA0, iA1, iA2, iA3, kA0, kA1, kA2, kA3, vA0, vA1, vA2, vA3);
        if (nb > 1) LOADIDS(p + 8, iB0, iB1, iB2, iB3);
    }
    int b = 0;
    for (; b + 2 <= nb; b += 2) {
        // KV for block b+1 (ids landed one compute-block ago)
        ISSUEKV(iB0, iB1, iB2, iB3, kB0, kB1, kB2, kB3, vB0, vB1, vB2, vB3);
        // ids for block b+2 (reuses idsA regs; kvA already issued)
        if (b + 2 < nb) LOADIDS(p + 16, iA0, iA1, iA2, iA3);
        COMPUTE(kA0, kA1, kA2, kA3, vA0, vA1, vA2, vA3);          // block b
        // KV for block b+2 (ids had one compute-block of cover)
        if (b + 2 < nb) ISSUEKV(iA0, iA1, iA2, iA3, kA0, kA1, kA2, kA3, vA0, vA1, vA2, vA3);
        // ids for block b+3
        if (b + 3 < nb) LOADIDS(p + 24, iB0, iB1, iB2, iB3);
        COMPUTE(kB0, kB1, kB2, kB3, vB0, vB1, vB2, vB3);          // block b+1
        p += 16;
    }
    if (b < nb) {                        // odd leftover block (set A loaded)
        COMPUTE(kA0, kA1, kA2, kA3, vA0, vA1, vA2, vA3);
        p += 8;
    }

    for (; p < s1; p += 2) {              // tail: 1 edge per half, predicated
        int e = p + half;
        bool ok = e < s1;
        int sa = csr_src[ok ? e : (s1 - 1)];
        const unsigned* ra = Cu + (long)sa * 256;
        unsigned ka = ra[128 + sl];
        uint2 va = *(const uint2*)(ra + 160 + 2 * sl);
        fx2 a01 = __builtin_amdgcn_cvt_pk_f32_fp8((int)ka, false);
        fx2 a23 = __builtin_amdgcn_cvt_pk_f32_fp8((int)ka, true);
        float pa = q4.x * a01.x + q4.y * a01.y + q4.z * a23.x + q4.w * a23.y;
        pa += __shfl_xor(pa, 1); pa += __shfl_xor(pa, 2); pa += __shfl_xor(pa, 4);
        float wa = ok ? __expf(pa) : 0.f;
        lsum += wa;
        a0 += wa * blo(va.x);
        a1 += wa * bhi(va.x);
        a2 += wa * blo(va.y);
        a3 += wa * bhi(va.y);
    }
#undef LOADIDS
#undef ISSUEKV
#undef COMPUTE

    lsum += __shfl_xor(lsum, 32);
    a0 += __shfl_xor(a0, 32);
    a1 += __shfl_xor(a1, 32);
    a2 += __shfl_xor(a2, 32);
    a3 += __shfl_xor(a3, 32);
    if (lane < 32) {
        float inv = 1.f / (lsum + 1e-8f);
        float4 o;
        o.x = a0 * inv; o.y = a1 * inv; o.z = a2 * inv; o.w = a3 * inv;
        *(float4*)&agg[(long)d * 128 + 4 * sl] = o;
    }
}

// Output GEMM (fp32): out = relu(A[M x 128] @ B[128 x 128]^T + bias)
__global__ __launch_bounds__(256) void k_gemm(const float* __restrict__ A,
                                              const float* __restrict__ B,
                                              const float* __restrict__ bias,
                                              float* __restrict__ Cp, int M) {
    __shared__ float As[32][64];
    __shared__ float Bs[32][64];
    const int m0 = blockIdx.x * 64, n0 = blockIdx.y * 64;
    const int t = threadIdx.x;
    const int tm = (t & 15) * 4, tn = (t >> 4) * 4;
    float acc[4][4] = {};
    for (int k0 = 0; k0 < 128; k0 += 32) {
#pragma unroll
        for (int i = 0; i < 2; ++i) {
            int idx = t + i * 256;
            int row = idx >> 3;
            int c4 = (idx & 7) * 4;
            float4 fa = make_float4(0.f, 0.f, 0.f, 0.f);
            if (m0 + row < M) fa = *(const float4*)&A[(long)(m0 + row) * 128 + k0 + c4];
            As[c4 + 0][row] = fa.x; As[c4 + 1][row] = fa.y;
            As[c4 + 2][row] = fa.z; As[c4 + 3][row] = fa.w;
            float4 fb = *(const float4*)&B[(long)(n0 + row) * 128 + k0 + c4];
            Bs[c4 + 0][row] = fb.x; Bs[c4 + 1][row] = fb.y;
            Bs[c4 + 2][row] = fb.z; Bs[c4 + 3][row] = fb.w;
        }
        __syncthreads();
#pragma unroll
        for (int k = 0; k < 32; ++k) {
            float4 a = *(const float4*)&As[k][tm];
            float4 b = *(const float4*)&Bs[k][tn];
            acc[0][0] += a.x * b.x; acc[0][1] += a.x * b.y; acc[0][2] += a.x * b.z; acc[0][3] += a.x * b.w;
            acc[1][0] += a.y * b.x; acc[1][1] += a.y * b.y; acc[1][2] += a.y * b.z; acc[1][3] += a.y * b.w;
            acc[2][0] += a.z * b.x; acc[2][1] += a.z * b.y; acc[2][2] += a.z * b.z; acc[2][3] += a.z * b.w;
            acc[3][0] += a.w * b.x; acc[3][1] += a.w * b.y; acc[3][2] += a.w * b.z; acc[3][3] += a.w * b.w;
        }
        __syncthreads();
    }
    float4 bv4 = *(const float4*)&bias[n0 + tn];
#pragma unroll
    for (int i = 0; i < 4; ++i) {
        int m = m0 + tm + i;
        if (m >= M) continue;
        float4 o;
        o.x = fmaxf(acc[i][0] + bv4.x, 0.f); o.y = fmaxf(acc[i][1] + bv4.y, 0.f);
        o.z = fmaxf(acc[i][2] + bv4.z, 0.f); o.w = fmaxf(acc[i][3] + bv4.w, 0.f);
        *(float4*)&Cp[(long)m * 128 + n0 + tn] = o;
    }
}

extern "C" void kernel_launch(void* const* d_in, const int* in_sizes, int n_in,
                              void* d_out, int out_size, void* d_ws, size_t ws_size,
                              hipStream_t stream) {
    const float* x  = (const float*)d_in[0];
    const int* edge = (const int*)d_in[1];
    const float* Wq = (const float*)d_in[2];
    const float* bq = (const float*)d_in[3];
    const float* Wk = (const float*)d_in[4];
    const float* bk = (const float*)d_in[5];
    const float* Wv = (const float*)d_in[6];
    const float* bv = (const float*)d_in[7];
    const float* Wo = (const float*)d_in[8];
    const float* bo = (const float*)d_in[9];
    float* out = (float*)d_out;

    char* ws = (char*)d_ws;
    unsigned short* Wcatb = (unsigned short*)(ws + OFF_WCATB);
    float* bcat      = (float*)(ws + OFF_BCAT);
    unsigned short* xb = (unsigned short*)(ws + OFF_XB);
    unsigned* Cu     = (unsigned*)(ws + OFF_C);
    unsigned short* csr_src = (unsigned short*)(ws + OFF_SRC);
    unsigned* bucketed = (unsigned*)(ws + OFF_BKD);
    int*   cnt       = (int*)(ws + OFF_CNT);
    int*   bsum      = (int*)(ws + OFF_BSUM);
    int*   bktoff    = (int*)(ws + OFF_BOFF);
    int*   row_start = (int*)(ws + OFF_RS);
    float* agg       = (float*)(ws + OFF_AGG);

    const int* srcA = edge;
    const int* dstA = edge + N_EDGES;

    // D1: coarse bucket hist (LDS) || x->bf16 || weight prep
    k_prep<<<PREP_GRID, 256, 0, stream>>>(
        x, xb, Wq, bq, Wk, bk, Wv, bv, Wcatb, bcat, dstA, cnt);

    // D2: tiny scans -> per-(bucket,block) absolute offsets
    k_b2a<<<NBKT, 256, 0, stream>>>(cnt, bsum);
    k_b2b<<<1, 256, 0, stream>>>(bsum, bktoff);
    k_b2c<<<NBKT, 256, 0, stream>>>(cnt, bktoff);

    // D3: QKV MFMA GEMM || bucket scatter (LDS cursors)
    k_gemmqkv_b3<<<GB3_GRID, 256, 0, stream>>>(
        xb, Wcatb, bcat, Cu, N_NODES, srcA, dstA, cnt, bucketed);

    // D4: per-bucket fine counting sort -> csr_src + row_start
    k_b4<<<NBKT, 256, 0, stream>>>(bucketed, bktoff, csr_src, row_start);

    // D5: fused scores + softmax + V aggregate
    k_attn<<<(N_NODES + 3) / 4, 256, 0, stream>>>(Cu, row_start, csr_src, agg);

    // D6: out = relu(agg @ Wo^T + bo)
    k_gemm<<<dim3((N_NODES + 63) / 64, 2), 256, 0, stream>>>(agg, Wo, bo, out, N_NODES);
}

// Round 2
// 289.630 us; speedup vs baseline: 1.0148x; 1.0148x over previous
//
#include <hip/hip_runtime.h>

#define N_NODES 50000
#define N_EDGES 1600000
#define DIM 128
#define M_PAD 50048    // 782 * 64
#define NBKT 196       // buckets = dst >> 8
#define CHUNK 6250     // edges per build block
#define BB 256         // build blocks (BB * CHUNK == N_EDGES)

// ---------------- workspace layout (bytes) ----------------
// C layout per node: 1024 B = [Q: 128 fp32 | u32 0..127]
//                             [KV interleaved | u32 128..223: per lane sl (0..31)
//                              3 words at 128+3*sl = {K fp8x4, V bf16x2, V bf16x2}]
//                             [pad u32 224..255]
#define OFF_WCATB  0UL                    // 384*128*2   = 98304
#define OFF_BCAT   98304UL                // 384*4       = 1536
#define OFF_XB     99840UL                // 50048*128*2 = 12812288
#define OFF_C      12912128UL             // 50000*1024  = 51200000
#define OFF_SRC    64112128UL             // 1600000*2   = 3200000   (csr src ids, u16)
#define OFF_BKD    67312128UL             // 1600000*4   = 6400000   (bucketed (dloc<<16)|src)
#define OFF_CNT    73712128UL             // 196*256*4   = 200704    (per-(bucket,block) counts/offsets)
#define OFF_BSUM   73912832UL             // 196*4
#define OFF_BOFF   73913664UL             // 197*4       (bucket offsets)
#define OFF_RS     73914496UL             // 50001*4
#define OFF_AGG    74114560UL             // 50000*128*4 = 25600000  -> total ~99.7 MB

typedef __attribute__((ext_vector_type(8))) short short8;    // 8 bf16
typedef __attribute__((ext_vector_type(4))) float floatx4;   // MFMA acc
typedef __attribute__((ext_vector_type(2))) float fx2;       // packed fp8 cvt result

__device__ __forceinline__ unsigned bf16r(float f) {   // fp32 -> bf16 bits, RNE
    unsigned u = __float_as_uint(f);
    return (u + 0x7fffu + ((u >> 16) & 1u)) >> 16;
}
__device__ __forceinline__ unsigned pack2(float a, float b) {
    return bf16r(a) | (bf16r(b) << 16);
}
__device__ __forceinline__ float blo(unsigned v) { return __uint_as_float(v << 16); }
__device__ __forceinline__ float bhi(unsigned v) { return __uint_as_float(v & 0xffff0000u); }

// ---- D1: coarse bucket hist (LDS) | x->bf16 cvt | weight prep ----
#define CVT_NB 6250
#define PREPW_NB 192
#define PREP_GRID (BB + CVT_NB + PREPW_NB)   // 6698
__global__ __launch_bounds__(256) void k_prep(const float* __restrict__ x,
                                              unsigned short* __restrict__ xb,
                                              const float* __restrict__ Wq, const float* __restrict__ bq,
                                              const float* __restrict__ Wk, const float* __restrict__ bk,
                                              const float* __restrict__ Wv, const float* __restrict__ bv,
                                              unsigned short* __restrict__ Wcatb,
                                              float* __restrict__ bcat,
                                              const int* __restrict__ dstA,
                                              int* __restrict__ cnt) {
    __shared__ int h[NBKT];
    int bx = blockIdx.x, t = threadIdx.x;
    if (bx < BB) {                       // coarse hist: 196 LDS bins
        if (t < NBKT) h[t] = 0;
        __syncthreads();
        int base = bx * CHUNK;
        for (int i = t; i < CHUNK; i += 256)
            atomicAdd(&h[dstA[base + i] >> 8], 1);
        __syncthreads();
        if (t < NBKT) cnt[t * BB + bx] = h[t];
    } else if (bx < BB + CVT_NB) {       // cvt: one float4 per thread
        int i = (bx - BB) * 256 + t;
        if (i < N_NODES * DIM / 4) {
            float4 f = ((const float4*)x)[i];
            ushort4 o;
            o.x = (unsigned short)bf16r(f.x); o.y = (unsigned short)bf16r(f.y);
            o.z = (unsigned short)bf16r(f.z); o.w = (unsigned short)bf16r(f.w);
            ((ushort4*)xb)[i] = o;
        }
    } else {                             // weight prep
        int i = (bx - BB - CVT_NB) * 256 + t;
        if (i < 3 * DIM * DIM) {
            int ro = i >> 7, col = i & 127;
            const float* W = (ro < 128) ? Wq : (ro < 256) ? Wk : Wv;
            Wcatb[i] = (unsigned short)bf16r(W[(ro & 127) * DIM + col]);
        }
        if (i < 3 * DIM) {
            const float* b = (i < 128) ? bq : (i < 256) ? bk : bv;
            bcat[i] = b[i & 127];
        }
    }
}

// ---- tiny scans over the 196x256 count matrix ----
__global__ __launch_bounds__(256) void k_b2a(const int* __restrict__ cnt, int* __restrict__ bsum) {
    __shared__ int red[256];
    int t = threadIdx.x;
    red[t] = cnt[blockIdx.x * BB + t];
    __syncthreads();
    for (int off = 128; off > 0; off >>= 1) {
        if (t < off) red[t] += red[t + off];
        __syncthreads();
    }
    if (t == 0) bsum[blockIdx.x] = red[0];
}
__global__ __launch_bounds__(256) void k_b2b(const int* __restrict__ bsum, int* __restrict__ bktoff) {
    __shared__ int s[256];
    int t = threadIdx.x;
    int v = (t < NBKT) ? bsum[t] : 0;
    s[t] = v;
    __syncthreads();
    for (int off = 1; off < 256; off <<= 1) {
        int u = (t >= off) ? s[t - off] : 0;
        __syncthreads();
        s[t] += u;
        __syncthreads();
    }
    if (t < NBKT) bktoff[t] = s[t] - v;
    if (t == NBKT - 1) bktoff[NBKT] = s[t];
}
__global__ __launch_bounds__(256) void k_b2c(int* __restrict__ cnt, const int* __restrict__ bktoff) {
    __shared__ int s[256];
    int t = threadIdx.x;
    int v = cnt[blockIdx.x * BB + t];
    s[t] = v;
    __syncthreads();
    for (int off = 1; off < 256; off <<= 1) {
        int u = (t >= off) ? s[t - off] : 0;
        __syncthreads();
        s[t] += u;
        __syncthreads();
    }
    cnt[blockIdx.x * BB + t] = bktoff[blockIdx.x] + s[t] - v;   // absolute offset
}

// ---- D3: QKV MFMA GEMM interleaved 18:1 with bucket scatter (no global atomics) ----
#define GQ_MB (M_PAD / 64)          // 782
#define GQ_BLOCKS (GQ_MB * 6)       // 4692
#define GB3_GRPS 261
#define GB3_GRID (GB3_GRPS * 19)    // 4959
__global__ __launch_bounds__(256) void k_gemmqkv_b3(const unsigned short* __restrict__ xb,
                                                    const unsigned short* __restrict__ Wb,
                                                    const float* __restrict__ bias,
                                                    unsigned* __restrict__ Cu, int M,
                                                    const int* __restrict__ srcA,
                                                    const int* __restrict__ dstA,
                                                    const int* __restrict__ cnt,
                                                    unsigned* __restrict__ bucketed) {
    __shared__ __align__(16) unsigned short As[64][136];
    __shared__ __align__(16) unsigned short Bs[64][136];
    __shared__ int cur[NBKT];
    const int grp = blockIdx.x / 19, r = blockIdx.x % 19;
    const int t = threadIdx.x;
    if (r == 18) {                      // bucket scatter block
        if (grp < BB) {
            if (t < NBKT) cur[t] = cnt[t * BB + grp];
            __syncthreads();
            int base = grp * CHUNK;
            for (int i = t; i < CHUNK; i += 256) {
                int e = base + i;
                int d = dstA[e];
                int p = atomicAdd(&cur[d >> 8], 1);       // LDS
                bucketed[p] = (unsigned)srcA[e] | ((unsigned)(d & 255) << 16);
            }
        }
        return;
    }
    const int g = grp * 18 + r;
    if (g >= GQ_BLOCKS) return;
    const int m0 = (g % GQ_MB) * 64, n0 = (g / GQ_MB) * 64;
    {
        int row = t >> 2, ch = t & 3;
        const uint4* xrow = (const uint4*)(xb + (long)(m0 + row) * 128);
        const uint4* wrow = (const uint4*)(Wb + (long)(n0 + row) * 128);
#pragma unroll
        for (int j = 0; j < 4; ++j) {
            *(uint4*)&As[row][(ch + 4 * j) * 8] = xrow[ch + 4 * j];
            *(uint4*)&Bs[row][(ch + 4 * j) * 8] = wrow[ch + 4 * j];
        }
    }
    __syncthreads();
    const int w = t >> 6, lane = t & 63;
    const int quad = lane >> 4, c = lane & 15;
    floatx4 acc[4] = {{0.f,0.f,0.f,0.f},{0.f,0.f,0.f,0.f},{0.f,0.f,0.f,0.f},{0.f,0.f,0.f,0.f}};
#pragma unroll
    for (int ks = 0; ks < 4; ++ks) {
        short8 a = *(const short8*)&As[w * 16 + c][ks * 32 + quad * 8];
#pragma unroll
        for (int nt = 0; nt < 4; ++nt) {
            short8 b = *(const short8*)&Bs[nt * 16 + c][ks * 32 + quad * 8];
            acc[nt] = __builtin_amdgcn_mfma_f32_16x16x32_bf16(a, b, acc[nt], 0, 0, 0);
        }
    }
#pragma unroll
    for (int nt = 0; nt < 4; ++nt) {
        int gn = n0 + nt * 16 + c;
        float bv = bias[gn];
        int slice = gn >> 7;           // 0=Q 1=K(fp8) 2=V(bf16)
        int cs = gn & 127;
#pragma unroll
        for (int i = 0; i < 4; ++i) {
            int gm = m0 + w * 16 + quad * 4 + i;
            float o = acc[nt][i] + bv;
            float f1 = __shfl_xor(o, 1);
            float f2 = __shfl_xor(o, 2);
            float f3 = __shfl_xor(o, 3);
            if (gm < M) {
                unsigned* crow = Cu + (long)gm * 256;
                if (slice == 0) {
                    ((float*)crow)[cs] = o;
                } else if (slice == 1) {
                    // K word j = cs>>2 (lane sl=j) -> interleaved slot 128 + 3*j
                    if ((c & 3) == 0) {
                        int pk = __builtin_amdgcn_cvt_pk_fp8_f32(o, f1, 0, false);
                        pk = __builtin_amdgcn_cvt_pk_fp8_f32(f2, f3, pk, true);
                        crow[128 + 3 * (cs >> 2)] = (unsigned)pk;
                    }
                } else {
                    // V word j = cs>>1 (j=2*sl or 2*sl+1) -> 128 + 3*(j>>1) + 1 + (j&1)
                    if ((c & 1) == 0) {
                        int j = cs >> 1;
                        crow[128 + 3 * (j >> 1) + 1 + (j & 1)] = pack2(o, f1);
                    }
                }
            }
        }
    }
}

// ---- D4: per-bucket fine sort -> csr_src + row_start (all LDS atomics) ----
__global__ __launch_bounds__(256) void k_b4(const unsigned* __restrict__ bucketed,
                                            const int* __restrict__ bktoff,
                                            unsigned short* __restrict__ csr_src,
                                            int* __restrict__ row_start) {
    __shared__ int h[256], s[256], cur[256];
    int b = blockIdx.x, t = threadIdx.x;
    int base = bktoff[b], end = bktoff[b + 1];
    h[t] = 0;
    __syncthreads();
    for (int p = base + t; p < end; p += 256)
        atomicAdd(&h[bucketed[p] >> 16], 1);
    __syncthreads();
    int v = h[t];
    s[t] = v;
    __syncthreads();
    for (int off = 1; off < 256; off <<= 1) {
        int u = (t >= off) ? s[t - off] : 0;
        __syncthreads();
        s[t] += u;
        __syncthreads();
    }
    int start = base + s[t] - v;
    int d = b * 256 + t;
    if (d < N_NODES) row_start[d] = start;
    if (d == N_NODES - 1) row_start[N_NODES] = N_EDGES;
    cur[t] = start;
    __syncthreads();
    for (int p = base + t; p < end; p += 256) {
        unsigned u = bucketed[p];
        int q = atomicAdd(&cur[u >> 16], 1);              // LDS
        csr_src[q] = (unsigned short)(u & 0xffffu);
    }
}

// ---- fused scores+softmax+aggregate, half-wave layout, no max shift ----
// v3: round-0 loop structure (the v2 hand pipeline forced vmcnt(0) drains
// because ids were consumed right after issue -> reverted). New: K/V
// interleaved per lane (3 words at 128+3*sl), so each edge needs ONE
// address chain + loads at imm offsets 0/4/8 instead of two independent
// address computations. Same 3 cache lines (384 B) per edge.
__global__ __launch_bounds__(256) void k_attn(const unsigned* __restrict__ Cu,
                                              const int* __restrict__ row_start,
                                              const unsigned short* __restrict__ csr_src,
                                              float* __restrict__ agg) {
    int d = blockIdx.x * 4 + (threadIdx.x >> 6);
    int lane = threadIdx.x & 63;
    if (d >= N_NODES) return;
    const int half = lane >> 5, sl = lane & 31;
    const float scale = 0.17677669529663687f;   // 1/sqrt(32), folded into q
    float4 q4 = *(const float4*)((const float*)(Cu + (long)d * 256) + 4 * sl);
    q4.x *= scale; q4.y *= scale; q4.z *= scale; q4.w *= scale;
    int s0 = row_start[d], s1 = row_start[d + 1];
    float lsum = 0.f, a0 = 0.f, a1 = 0.f, a2 = 0.f, a3 = 0.f;
    const int kvoff = 128 + 3 * sl;             // per-lane KV base word
    int pos = s0;
    for (; pos + 8 <= s1; pos += 8) {         // 4 edges per half
        int base = pos + half * 4;
        int sa = csr_src[base + 0];
        int sb = csr_src[base + 1];
        int sc2 = csr_src[base + 2];
        int sd = csr_src[base + 3];
        const unsigned* ra = Cu + (long)sa * 256 + kvoff;
        const unsigned* rb = Cu + (long)sb * 256 + kvoff;
        const unsigned* rc = Cu + (long)sc2 * 256 + kvoff;
        const unsigned* rd = Cu + (long)sd * 256 + kvoff;
        unsigned ka = ra[0];
        unsigned kb = rb[0];
        unsigned kc = rc[0];
        unsigned kd = rd[0];
        uint2 va; va.x = ra[1]; va.y = ra[2];
        uint2 vb; vb.x = rb[1]; vb.y = rb[2];
        uint2 vc; vc.x = rc[1]; vc.y = rc[2];
        uint2 vd; vd.x = rd[1]; vd.y = rd[2];
        fx2 a01 = __builtin_amdgcn_cvt_pk_f32_fp8((int)ka, false);
        fx2 a23 = __builtin_amdgcn_cvt_pk_f32_fp8((int)ka, true);
        fx2 b01 = __builtin_amdgcn_cvt_pk_f32_fp8((int)kb, false);
        fx2 b23 = __builtin_amdgcn_cvt_pk_f32_fp8((int)kb, true);
        fx2 c01 = __builtin_amdgcn_cvt_pk_f32_fp8((int)kc, false);
        fx2 c23 = __builtin_amdgcn_cvt_pk_f32_fp8((int)kc, true);
        fx2 d01 = __builtin_amdgcn_cvt_pk_f32_fp8((int)kd, false);
        fx2 d23 = __builtin_amdgcn_cvt_pk_f32_fp8((int)kd, true);
        float pa = q4.x * a01.x + q4.y * a01.y + q4.z * a23.x + q4.w * a23.y;
        float pb = q4.x * b01.x + q4.y * b01.y + q4.z * b23.x + q4.w * b23.y;
        float pc = q4.x * c01.x + q4.y * c01.y + q4.z * c23.x + q4.w * c23.y;
        float pd = q4.x * d01.x + q4.y * d01.y + q4.z * d23.x + q4.w * d23.y;
        pa += __shfl_xor(pa, 1); pa += __shfl_xor(pa, 2); pa += __shfl_xor(pa, 4);
        pb += __shfl_xor(pb, 1); pb += __shfl_xor(pb, 2); pb += __shfl_xor(pb, 4);
        pc += __shfl_xor(pc, 1); pc += __shfl_xor(pc, 2); pc += __shfl_xor(pc, 4);
        pd += __shfl_xor(pd, 1); pd += __shfl_xor(pd, 2); pd += __shfl_xor(pd, 4);
        float wa = __expf(pa), wb = __expf(pb), wc = __expf(pc), wd = __expf(pd);
        lsum += (wa + wb) + (wc + wd);
        a0 += wa * blo(va.x) + wb * blo(vb.x) + wc * blo(vc.x) + wd * blo(vd.x);
        a1 += wa * bhi(va.x) + wb * bhi(vb.x) + wc * bhi(vc.x) + wd * bhi(vd.x);
        a2 += wa * blo(va.y) + wb * blo(vb.y) + wc * blo(vc.y) + wd * blo(vd.y);
        a3 += wa * bhi(va.y) + wb * bhi(vb.y) + wc * bhi(vc.y) + wd * bhi(vd.y);
    }
    for (; pos < s1; pos += 2) {              // tail: 1 edge per half, predicated
        int e = pos + half;
        bool ok = e < s1;
        int sa = csr_src[ok ? e : (s1 - 1)];
        const unsigned* ra = Cu + (long)sa * 256 + kvoff;
        unsigned ka = ra[0];
        uint2 va; va.x = ra[1]; va.y = ra[2];
        fx2 a01 = __builtin_amdgcn_cvt_pk_f32_fp8((int)ka, false);
        fx2 a23 = __builtin_amdgcn_cvt_pk_f32_fp8((int)ka, true);
        float pa = q4.x * a01.x + q4.y * a01.y + q4.z * a23.x + q4.w * a23.y;
        pa += __shfl_xor(pa, 1); pa += __shfl_xor(pa, 2); pa += __shfl_xor(pa, 4);
        float wa = ok ? __expf(pa) : 0.f;
        lsum += wa;
        a0 += wa * blo(va.x);
        a1 += wa * bhi(va.x);
        a2 += wa * blo(va.y);
        a3 += wa * bhi(va.y);
    }
    lsum += __shfl_xor(lsum, 32);
    a0 += __shfl_xor(a0, 32);
    a1 += __shfl_xor(a1, 32);
    a2 += __shfl_xor(a2, 32);
    a3 += __shfl_xor(a3, 32);
    if (lane < 32) {
        float inv = 1.f / (lsum + 1e-8f);
        float4 o;
        o.x = a0 * inv; o.y = a1 * inv; o.z = a2 * inv; o.w = a3 * inv;
        *(float4*)&agg[(long)d * 128 + 4 * sl] = o;
    }
}

// Output GEMM (fp32): out = relu(A[M x 128] @ B[128 x 128]^T + bias)
__global__ __launch_bounds__(256) void k_gemm(const float* __restrict__ A,
                                              const float* __restrict__ B,
                                              const float* __restrict__ bias,
                                              float* __restrict__ Cp, int M) {
    __shared__ float As[32][64];
    __shared__ float Bs[32][64];
    const int m0 = blockIdx.x * 64, n0 = blockIdx.y * 64;
    const int t = threadIdx.x;
    const int tm = (t & 15) * 4, tn = (t >> 4) * 4;
    float acc[4][4] = {};
    for (int k0 = 0; k0 < 128; k0 += 32) {
#pragma unroll
        for (int i = 0; i < 2; ++i) {
            int idx = t + i * 256;
            int row = idx >> 3;
            int c4 = (idx & 7) * 4;
            float4 fa = make_float4(0.f, 0.f, 0.f, 0.f);
            if (m0 + row < M) fa = *(const float4*)&A[(long)(m0 + row) * 128 + k0 + c4];
            As[c4 + 0][row] = fa.x; As[c4 + 1][row] = fa.y;
            As[c4 + 2][row] = fa.z; As[c4 + 3][row] = fa.w;
            float4 fb = *(const float4*)&B[(long)(n0 + row) * 128 + k0 + c4];
            Bs[c4 + 0][row] = fb.x; Bs[c4 + 1][row] = fb.y;
            Bs[c4 + 2][row] = fb.z; Bs[c4 + 3][row] = fb.w;
        }
        __syncthreads();
#pragma unroll
        for (int k = 0; k < 32; ++k) {
            float4 a = *(const float4*)&As[k][tm];
            float4 b = *(const float4*)&Bs[k][tn];
            acc[0][0] += a.x * b.x; acc[0][1] += a.x * b.y; acc[0][2] += a.x * b.z; acc[0][3] += a.x * b.w;
            acc[1][0] += a.y * b.x; acc[1][1] += a.y * b.y; acc[1][2] += a.y * b.z; acc[1][3] += a.y * b.w;
            acc[2][0] += a.z * b.x; acc[2][1] += a.z * b.y; acc[2][2] += a.z * b.z; acc[2][3] += a.z * b.w;
            acc[3][0] += a.w * b.x; acc[3][1] += a.w * b.y; acc[3][2] += a.w * b.z; acc[3][3] += a.w * b.w;
        }
        __syncthreads();
    }
    float4 bv4 = *(const float4*)&bias[n0 + tn];
#pragma unroll
    for (int i = 0; i < 4; ++i) {
        int m = m0 + tm + i;
        if (m >= M) continue;
        float4 o;
        o.x = fmaxf(acc[i][0] + bv4.x, 0.f); o.y = fmaxf(acc[i][1] + bv4.y, 0.f);
        o.z = fmaxf(acc[i][2] + bv4.z, 0.f); o.w = fmaxf(acc[i][3] + bv4.w, 0.f);
        *(float4*)&Cp[(long)m * 128 + n0 + tn] = o;
    }
}

extern "C" void kernel_launch(void* const* d_in, const int* in_sizes, int n_in,
                              void* d_out, int out_size, void* d_ws, size_t ws_size,
                              hipStream_t stream) {
    const float* x  = (const float*)d_in[0];
    const int* edge = (const int*)d_in[1];
    const float* Wq = (const float*)d_in[2];
    const float* bq = (const float*)d_in[3];
    const float* Wk = (const float*)d_in[4];
    const float* bk = (const float*)d_in[5];
    const float* Wv = (const float*)d_in[6];
    const float* bv = (const float*)d_in[7];
    const float* Wo = (const float*)d_in[8];
    const float* bo = (const float*)d_in[9];
    float* out = (float*)d_out;

    char* ws = (char*)d_ws;
    unsigned short* Wcatb = (unsigned short*)(ws + OFF_WCATB);
    float* bcat      = (float*)(ws + OFF_BCAT);
    unsigned short* xb = (unsigned short*)(ws + OFF_XB);
    unsigned* Cu     = (unsigned*)(ws + OFF_C);
    unsigned short* csr_src = (unsigned short*)(ws + OFF_SRC);
    unsigned* bucketed = (unsigned*)(ws + OFF_BKD);
    int*   cnt       = (int*)(ws + OFF_CNT);
    int*   bsum      = (int*)(ws + OFF_BSUM);
    int*   bktoff    = (int*)(ws + OFF_BOFF);
    int*   row_start = (int*)(ws + OFF_RS);
    float* agg       = (float*)(ws + OFF_AGG);

    const int* srcA = edge;
    const int* dstA = edge + N_EDGES;

    // D1: coarse bucket hist (LDS) || x->bf16 || weight prep
    k_prep<<<PREP_GRID, 256, 0, stream>>>(
        x, xb, Wq, bq, Wk, bk, Wv, bv, Wcatb, bcat, dstA, cnt);

    // D2: tiny scans -> per-(bucket,block) absolute offsets
    k_b2a<<<NBKT, 256, 0, stream>>>(cnt, bsum);
    k_b2b<<<1, 256, 0, stream>>>(bsum, bktoff);
    k_b2c<<<NBKT, 256, 0, stream>>>(cnt, bktoff);

    // D3: QKV MFMA GEMM || bucket scatter (LDS cursors)
    k_gemmqkv_b3<<<GB3_GRID, 256, 0, stream>>>(
        xb, Wcatb, bcat, Cu, N_NODES, srcA, dstA, cnt, bucketed);

    // D4: per-bucket fine counting sort -> csr_src + row_start
    k_b4<<<NBKT, 256, 0, stream>>>(bucketed, bktoff, csr_src, row_start);

    // D5: fused scores + softmax + V aggregate
    k_attn<<<(N_NODES + 3) / 4, 256, 0, stream>>>(Cu, row_start, csr_src, agg);

    // D6: out = relu(agg @ Wo^T + bo)
    k_gemm<<<dim3((N_NODES + 63) / 64, 2), 256, 0, stream>>>(agg, Wo, bo, out, N_NODES);
}

// Round 3
// 271.909 us; speedup vs baseline: 1.0810x; 1.0652x over previous
//
#include <hip/hip_runtime.h>

#define N_NODES 50000
#define N_EDGES 1600000
#define DIM 128
#define M_PAD 50048    // 782 * 64
#define NBKT 196       // buckets = dst >> 8
#define CHUNK 6250     // edges per build block
#define BB 256         // build blocks (BB * CHUNK == N_EDGES)

// ---------------- workspace layout (bytes) ----------------
// C layout per node: 1024 B = [Q: 128 fp32 | u32 0..127]
//                             [KV interleaved | u32 128..223: per lane sl (0..31)
//                              3 words at 128+3*sl = {K fp8x4, V bf16x2, V bf16x2}]
//                             [pad u32 224..255]
#define OFF_WCATB  0UL                    // 384*128*2   = 98304
#define OFF_BCAT   98304UL                // 384*4       = 1536
#define OFF_XB     99840UL                // 50048*128*2 = 12812288
#define OFF_C      12912128UL             // 50000*1024  = 51200000
#define OFF_SRC    64112128UL             // 1600000*2   = 3200000   (csr src ids, u16)
#define OFF_BKD    67312128UL             // 1600000*4   = 6400000   (bucketed (dloc<<16)|src)
#define OFF_CNT    73712128UL             // 196*256*4   = 200704    (per-(bucket,block) counts/offsets)
#define OFF_BSUM   73912832UL             // 196*4
#define OFF_BOFF   73913664UL             // 197*4       (bucket offsets)
#define OFF_RS     73914496UL             // 50001*4
#define OFF_AGG    74114560UL             // 50000*128*4 = 25600000  -> total ~99.7 MB

typedef __attribute__((ext_vector_type(8))) short short8;    // 8 bf16
typedef __attribute__((ext_vector_type(4))) float floatx4;   // MFMA acc
typedef __attribute__((ext_vector_type(2))) float fx2;       // packed fp8 cvt result

__device__ __forceinline__ unsigned bf16r(float f) {   // fp32 -> bf16 bits, RNE
    unsigned u = __float_as_uint(f);
    return (u + 0x7fffu + ((u >> 16) & 1u)) >> 16;
}
__device__ __forceinline__ unsigned pack2(float a, float b) {
    return bf16r(a) | (bf16r(b) << 16);
}
__device__ __forceinline__ float blo(unsigned v) { return __uint_as_float(v << 16); }
__device__ __forceinline__ float bhi(unsigned v) { return __uint_as_float(v & 0xffff0000u); }

// ---- D1: coarse bucket hist (LDS) | x->bf16 cvt | weight prep ----
#define CVT_NB 6250
#define PREPW_NB 192
#define PREP_GRID (BB + CVT_NB + PREPW_NB)   // 6698
__global__ __launch_bounds__(256) void k_prep(const float* __restrict__ x,
                                              unsigned short* __restrict__ xb,
                                              const float* __restrict__ Wq, const float* __restrict__ bq,
                                              const float* __restrict__ Wk, const float* __restrict__ bk,
                                              const float* __restrict__ Wv, const float* __restrict__ bv,
                                              unsigned short* __restrict__ Wcatb,
                                              float* __restrict__ bcat,
                                              const int* __restrict__ dstA,
                                              int* __restrict__ cnt) {
    __shared__ int h[NBKT];
    int bx = blockIdx.x, t = threadIdx.x;
    if (bx < BB) {                       // coarse hist: 196 LDS bins
        if (t < NBKT) h[t] = 0;
        __syncthreads();
        int base = bx * CHUNK;
        for (int i = t; i < CHUNK; i += 256)
            atomicAdd(&h[dstA[base + i] >> 8], 1);
        __syncthreads();
        if (t < NBKT) cnt[t * BB + bx] = h[t];
    } else if (bx < BB + CVT_NB) {       // cvt: one float4 per thread
        int i = (bx - BB) * 256 + t;
        if (i < N_NODES * DIM / 4) {
            float4 f = ((const float4*)x)[i];
            ushort4 o;
            o.x = (unsigned short)bf16r(f.x); o.y = (unsigned short)bf16r(f.y);
            o.z = (unsigned short)bf16r(f.z); o.w = (unsigned short)bf16r(f.w);
            ((ushort4*)xb)[i] = o;
        }
    } else {                             // weight prep
        int i = (bx - BB - CVT_NB) * 256 + t;
        if (i < 3 * DIM * DIM) {
            int ro = i >> 7, col = i & 127;
            const float* W = (ro < 128) ? Wq : (ro < 256) ? Wk : Wv;
            Wcatb[i] = (unsigned short)bf16r(W[(ro & 127) * DIM + col]);
        }
        if (i < 3 * DIM) {
            const float* b = (i < 128) ? bq : (i < 256) ? bk : bv;
            bcat[i] = b[i & 127];
        }
    }
}

// ---- tiny scans over the 196x256 count matrix ----
__global__ __launch_bounds__(256) void k_b2a(const int* __restrict__ cnt, int* __restrict__ bsum) {
    __shared__ int red[256];
    int t = threadIdx.x;
    red[t] = cnt[blockIdx.x * BB + t];
    __syncthreads();
    for (int off = 128; off > 0; off >>= 1) {
        if (t < off) red[t] += red[t + off];
        __syncthreads();
    }
    if (t == 0) bsum[blockIdx.x] = red[0];
}
__global__ __launch_bounds__(256) void k_b2b(const int* __restrict__ bsum, int* __restrict__ bktoff) {
    __shared__ int s[256];
    int t = threadIdx.x;
    int v = (t < NBKT) ? bsum[t] : 0;
    s[t] = v;
    __syncthreads();
    for (int off = 1; off < 256; off <<= 1) {
        int u = (t >= off) ? s[t - off] : 0;
        __syncthreads();
        s[t] += u;
        __syncthreads();
    }
    if (t < NBKT) bktoff[t] = s[t] - v;
    if (t == NBKT - 1) bktoff[NBKT] = s[t];
}
__global__ __launch_bounds__(256) void k_b2c(int* __restrict__ cnt, const int* __restrict__ bktoff) {
    __shared__ int s[256];
    int t = threadIdx.x;
    int v = cnt[blockIdx.x * BB + t];
    s[t] = v;
    __syncthreads();
    for (int off = 1; off < 256; off <<= 1) {
        int u = (t >= off) ? s[t - off] : 0;
        __syncthreads();
        s[t] += u;
        __syncthreads();
    }
    cnt[blockIdx.x * BB + t] = bktoff[blockIdx.x] + s[t] - v;   // absolute offset
}

// ---- D3: QKV MFMA GEMM interleaved 18:1 with bucket scatter (no global atomics) ----
#define GQ_MB (M_PAD / 64)          // 782
#define GQ_BLOCKS (GQ_MB * 6)       // 4692
#define GB3_GRPS 261
#define GB3_GRID (GB3_GRPS * 19)    // 4959
__global__ __launch_bounds__(256) void k_gemmqkv_b3(const unsigned short* __restrict__ xb,
                                                    const unsigned short* __restrict__ Wb,
                                                    const float* __restrict__ bias,
                                                    unsigned* __restrict__ Cu, int M,
                                                    const int* __restrict__ srcA,
                                                    const int* __restrict__ dstA,
                                                    const int* __restrict__ cnt,
                                                    unsigned* __restrict__ bucketed) {
    __shared__ __align__(16) unsigned short As[64][136];
    __shared__ __align__(16) unsigned short Bs[64][136];
    __shared__ int cur[NBKT];
    const int grp = blockIdx.x / 19, r = blockIdx.x % 19;
    const int t = threadIdx.x;
    if (r == 18) {                      // bucket scatter block
        if (grp < BB) {
            if (t < NBKT) cur[t] = cnt[t * BB + grp];
            __syncthreads();
            int base = grp * CHUNK;
            for (int i = t; i < CHUNK; i += 256) {
                int e = base + i;
                int d = dstA[e];
                int p = atomicAdd(&cur[d >> 8], 1);       // LDS
                bucketed[p] = (unsigned)srcA[e] | ((unsigned)(d & 255) << 16);
            }
        }
        return;
    }
    const int g = grp * 18 + r;
    if (g >= GQ_BLOCKS) return;
    const int m0 = (g % GQ_MB) * 64, n0 = (g / GQ_MB) * 64;
    {
        int row = t >> 2, ch = t & 3;
        const uint4* xrow = (const uint4*)(xb + (long)(m0 + row) * 128);
        const uint4* wrow = (const uint4*)(Wb + (long)(n0 + row) * 128);
#pragma unroll
        for (int j = 0; j < 4; ++j) {
            *(uint4*)&As[row][(ch + 4 * j) * 8] = xrow[ch + 4 * j];
            *(uint4*)&Bs[row][(ch + 4 * j) * 8] = wrow[ch + 4 * j];
        }
    }
    __syncthreads();
    const int w = t >> 6, lane = t & 63;
    const int quad = lane >> 4, c = lane & 15;
    floatx4 acc[4] = {{0.f,0.f,0.f,0.f},{0.f,0.f,0.f,0.f},{0.f,0.f,0.f,0.f},{0.f,0.f,0.f,0.f}};
#pragma unroll
    for (int ks = 0; ks < 4; ++ks) {
        short8 a = *(const short8*)&As[w * 16 + c][ks * 32 + quad * 8];
#pragma unroll
        for (int nt = 0; nt < 4; ++nt) {
            short8 b = *(const short8*)&Bs[nt * 16 + c][ks * 32 + quad * 8];
            acc[nt] = __builtin_amdgcn_mfma_f32_16x16x32_bf16(a, b, acc[nt], 0, 0, 0);
        }
    }
#pragma unroll
    for (int nt = 0; nt < 4; ++nt) {
        int gn = n0 + nt * 16 + c;
        float bv = bias[gn];
        int slice = gn >> 7;           // 0=Q 1=K(fp8) 2=V(bf16)
        int cs = gn & 127;
#pragma unroll
        for (int i = 0; i < 4; ++i) {
            int gm = m0 + w * 16 + quad * 4 + i;
            float o = acc[nt][i] + bv;
            float f1 = __shfl_xor(o, 1);
            float f2 = __shfl_xor(o, 2);
            float f3 = __shfl_xor(o, 3);
            if (gm < M) {
                unsigned* crow = Cu + (long)gm * 256;
                if (slice == 0) {
                    ((float*)crow)[cs] = o;
                } else if (slice == 1) {
                    // K word j = cs>>2 (lane sl=j) -> interleaved slot 128 + 3*j
                    if ((c & 3) == 0) {
                        int pk = __builtin_amdgcn_cvt_pk_fp8_f32(o, f1, 0, false);
                        pk = __builtin_amdgcn_cvt_pk_fp8_f32(f2, f3, pk, true);
                        crow[128 + 3 * (cs >> 2)] = (unsigned)pk;
                    }
                } else {
                    // V word j = cs>>1 (j=2*sl or 2*sl+1) -> 128 + 3*(j>>1) + 1 + (j&1)
                    if ((c & 1) == 0) {
                        int j = cs >> 1;
                        crow[128 + 3 * (j >> 1) + 1 + (j & 1)] = pack2(o, f1);
                    }
                }
            }
        }
    }
}

// ---- D4: per-bucket fine sort -> csr_src + row_start (all LDS atomics) ----
__global__ __launch_bounds__(256) void k_b4(const unsigned* __restrict__ bucketed,
                                            const int* __restrict__ bktoff,
                                            unsigned short* __restrict__ csr_src,
                                            int* __restrict__ row_start) {
    __shared__ int h[256], s[256], cur[256];
    int b = blockIdx.x, t = threadIdx.x;
    int base = bktoff[b], end = bktoff[b + 1];
    h[t] = 0;
    __syncthreads();
    for (int p = base + t; p < end; p += 256)
        atomicAdd(&h[bucketed[p] >> 16], 1);
    __syncthreads();
    int v = h[t];
    s[t] = v;
    __syncthreads();
    for (int off = 1; off < 256; off <<= 1) {
        int u = (t >= off) ? s[t - off] : 0;
        __syncthreads();
        s[t] += u;
        __syncthreads();
    }
    int start = base + s[t] - v;
    int d = b * 256 + t;
    if (d < N_NODES) row_start[d] = start;
    if (d == N_NODES - 1) row_start[N_NODES] = N_EDGES;
    cur[t] = start;
    __syncthreads();
    for (int p = base + t; p < end; p += 256) {
        unsigned u = bucketed[p];
        int q = atomicAdd(&cur[u >> 16], 1);              // LDS
        csr_src[q] = (unsigned short)(u & 0xffffu);
    }
}

// ---- fused scores+softmax+aggregate, half-wave layout, no max shift ----
// v3 layout: K/V interleaved per lane (3 words at 128+3*sl) -> one address
// chain per edge. Confirmed round 2: VALU work dropped but dur unchanged ->
// kernel is bound by L2-miss gather traffic (~3.65 TB/s, 258 MB). Left as-is.
__global__ __launch_bounds__(256) void k_attn(const unsigned* __restrict__ Cu,
                                              const int* __restrict__ row_start,
                                              const unsigned short* __restrict__ csr_src,
                                              float* __restrict__ agg) {
    int d = blockIdx.x * 4 + (threadIdx.x >> 6);
    int lane = threadIdx.x & 63;
    if (d >= N_NODES) return;
    const int half = lane >> 5, sl = lane & 31;
    const float scale = 0.17677669529663687f;   // 1/sqrt(32), folded into q
    float4 q4 = *(const float4*)((const float*)(Cu + (long)d * 256) + 4 * sl);
    q4.x *= scale; q4.y *= scale; q4.z *= scale; q4.w *= scale;
    int s0 = row_start[d], s1 = row_start[d + 1];
    float lsum = 0.f, a0 = 0.f, a1 = 0.f, a2 = 0.f, a3 = 0.f;
    const int kvoff = 128 + 3 * sl;             // per-lane KV base word
    int pos = s0;
    for (; pos + 8 <= s1; pos += 8) {         // 4 edges per half
        int base = pos + half * 4;
        int sa = csr_src[base + 0];
        int sb = csr_src[base + 1];
        int sc2 = csr_src[base + 2];
        int sd = csr_src[base + 3];
        const unsigned* ra = Cu + (long)sa * 256 + kvoff;
        const unsigned* rb = Cu + (long)sb * 256 + kvoff;
        const unsigned* rc = Cu + (long)sc2 * 256 + kvoff;
        const unsigned* rd = Cu + (long)sd * 256 + kvoff;
        unsigned ka = ra[0];
        unsigned kb = rb[0];
        unsigned kc = rc[0];
        unsigned kd = rd[0];
        uint2 va; va.x = ra[1]; va.y = ra[2];
        uint2 vb; vb.x = rb[1]; vb.y = rb[2];
        uint2 vc; vc.x = rc[1]; vc.y = rc[2];
        uint2 vd; vd.x = rd[1]; vd.y = rd[2];
        fx2 a01 = __builtin_amdgcn_cvt_pk_f32_fp8((int)ka, false);
        fx2 a23 = __builtin_amdgcn_cvt_pk_f32_fp8((int)ka, true);
        fx2 b01 = __builtin_amdgcn_cvt_pk_f32_fp8((int)kb, false);
        fx2 b23 = __builtin_amdgcn_cvt_pk_f32_fp8((int)kb, true);
        fx2 c01 = __builtin_amdgcn_cvt_pk_f32_fp8((int)kc, false);
        fx2 c23 = __builtin_amdgcn_cvt_pk_f32_fp8((int)kc, true);
        fx2 d01 = __builtin_amdgcn_cvt_pk_f32_fp8((int)kd, false);
        fx2 d23 = __builtin_amdgcn_cvt_pk_f32_fp8((int)kd, true);
        float pa = q4.x * a01.x + q4.y * a01.y + q4.z * a23.x + q4.w * a23.y;
        float pb = q4.x * b01.x + q4.y * b01.y + q4.z * b23.x + q4.w * b23.y;
        float pc = q4.x * c01.x + q4.y * c01.y + q4.z * c23.x + q4.w * c23.y;
        float pd = q4.x * d01.x + q4.y * d01.y + q4.z * d23.x + q4.w * d23.y;
        pa += __shfl_xor(pa, 1); pa += __shfl_xor(pa, 2); pa += __shfl_xor(pa, 4);
        pb += __shfl_xor(pb, 1); pb += __shfl_xor(pb, 2); pb += __shfl_xor(pb, 4);
        pc += __shfl_xor(pc, 1); pc += __shfl_xor(pc, 2); pc += __shfl_xor(pc, 4);
        pd += __shfl_xor(pd, 1); pd += __shfl_xor(pd, 2); pd += __shfl_xor(pd, 4);
        float wa = __expf(pa), wb = __expf(pb), wc = __expf(pc), wd = __expf(pd);
        lsum += (wa + wb) + (wc + wd);
        a0 += wa * blo(va.x) + wb * blo(vb.x) + wc * blo(vc.x) + wd * blo(vd.x);
        a1 += wa * bhi(va.x) + wb * bhi(vb.x) + wc * bhi(vc.x) + wd * bhi(vd.x);
        a2 += wa * blo(va.y) + wb * blo(vb.y) + wc * blo(vc.y) + wd * blo(vd.y);
        a3 += wa * bhi(va.y) + wb * bhi(vb.y) + wc * bhi(vc.y) + wd * bhi(vd.y);
    }
    for (; pos < s1; pos += 2) {              // tail: 1 edge per half, predicated
        int e = pos + half;
        bool ok = e < s1;
        int sa = csr_src[ok ? e : (s1 - 1)];
        const unsigned* ra = Cu + (long)sa * 256 + kvoff;
        unsigned ka = ra[0];
        uint2 va; va.x = ra[1]; va.y = ra[2];
        fx2 a01 = __builtin_amdgcn_cvt_pk_f32_fp8((int)ka, false);
        fx2 a23 = __builtin_amdgcn_cvt_pk_f32_fp8((int)ka, true);
        float pa = q4.x * a01.x + q4.y * a01.y + q4.z * a23.x + q4.w * a23.y;
        pa += __shfl_xor(pa, 1); pa += __shfl_xor(pa, 2); pa += __shfl_xor(pa, 4);
        float wa = ok ? __expf(pa) : 0.f;
        lsum += wa;
        a0 += wa * blo(va.x);
        a1 += wa * bhi(va.x);
        a2 += wa * blo(va.y);
        a3 += wa * bhi(va.y);
    }
    lsum += __shfl_xor(lsum, 32);
    a0 += __shfl_xor(a0, 32);
    a1 += __shfl_xor(a1, 32);
    a2 += __shfl_xor(a2, 32);
    a3 += __shfl_xor(a3, 32);
    if (lane < 32) {
        float inv = 1.f / (lsum + 1e-8f);
        float4 o;
        o.x = a0 * inv; o.y = a1 * inv; o.z = a2 * inv; o.w = a3 * inv;
        *(float4*)&agg[(long)d * 128 + 4 * sl] = o;
    }
}

// Output GEMM v2: MFMA bf16. out = relu(agg @ Wo^T + bo).
// Was vector-fp32 with a transposing LDS store (8-way bank conflicts) and no
// matrix cores (CDNA4 has no fp32 MFMA). Now: stage agg and Wo as bf16 (RNE,
// in-register cvt), fp32 MFMA accumulate — exact tile/fragment pattern copied
// from the harness-verified k_gemmqkv_b3. bf16 rounding of agg/Wo perturbs
// out by ~4e-4 (well under current absmax 4.9e-3).
__global__ __launch_bounds__(256) void k_gemm(const float* __restrict__ A,
                                              const float* __restrict__ B,
                                              const float* __restrict__ bias,
                                              float* __restrict__ Cp, int M) {
    __shared__ __align__(16) unsigned short As[64][136];
    __shared__ __align__(16) unsigned short Bs[64][136];
    const int m0 = blockIdx.x * 64, n0 = blockIdx.y * 64;
    const int t = threadIdx.x;
    {
        int row = t >> 2, ch = t & 3;
        const float* arow = A + (long)(m0 + row) * 128;
        const float* brow = B + (long)(n0 + row) * 128;
        bool aok = (m0 + row) < M;
#pragma unroll
        for (int j = 0; j < 4; ++j) {
            int c8 = (ch + 4 * j) * 8;
            uint4 av = {0u, 0u, 0u, 0u};
            if (aok) {
                float4 f0 = *(const float4*)(arow + c8);
                float4 f1 = *(const float4*)(arow + c8 + 4);
                av.x = pack2(f0.x, f0.y); av.y = pack2(f0.z, f0.w);
                av.z = pack2(f1.x, f1.y); av.w = pack2(f1.z, f1.w);
            }
            *(uint4*)&As[row][c8] = av;
            float4 g0 = *(const float4*)(brow + c8);
            float4 g1 = *(const float4*)(brow + c8 + 4);
            uint4 bv;
            bv.x = pack2(g0.x, g0.y); bv.y = pack2(g0.z, g0.w);
            bv.z = pack2(g1.x, g1.y); bv.w = pack2(g1.z, g1.w);
            *(uint4*)&Bs[row][c8] = bv;
        }
    }
    __syncthreads();
    const int w = t >> 6, lane = t & 63;
    const int quad = lane >> 4, c = lane & 15;
    floatx4 acc[4] = {{0.f,0.f,0.f,0.f},{0.f,0.f,0.f,0.f},{0.f,0.f,0.f,0.f},{0.f,0.f,0.f,0.f}};
#pragma unroll
    for (int ks = 0; ks < 4; ++ks) {
        short8 a = *(const short8*)&As[w * 16 + c][ks * 32 + quad * 8];
#pragma unroll
        for (int nt = 0; nt < 4; ++nt) {
            short8 b = *(const short8*)&Bs[nt * 16 + c][ks * 32 + quad * 8];
            acc[nt] = __builtin_amdgcn_mfma_f32_16x16x32_bf16(a, b, acc[nt], 0, 0, 0);
        }
    }
#pragma unroll
    for (int nt = 0; nt < 4; ++nt) {
        int gn = n0 + nt * 16 + c;
        float bv = bias[gn];
#pragma unroll
        for (int i = 0; i < 4; ++i) {
            int gm = m0 + w * 16 + quad * 4 + i;
            if (gm < M) Cp[(long)gm * 128 + gn] = fmaxf(acc[nt][i] + bv, 0.f);
        }
    }
}

extern "C" void kernel_launch(void* const* d_in, const int* in_sizes, int n_in,
                              void* d_out, int out_size, void* d_ws, size_t ws_size,
                              hipStream_t stream) {
    const float* x  = (const float*)d_in[0];
    const int* edge = (const int*)d_in[1];
    const float* Wq = (const float*)d_in[2];
    const float* bq = (const float*)d_in[3];
    const float* Wk = (const float*)d_in[4];
    const float* bk = (const float*)d_in[5];
    const float* Wv = (const float*)d_in[6];
    const float* bv = (const float*)d_in[7];
    const float* Wo = (const float*)d_in[8];
    const float* bo = (const float*)d_in[9];
    float* out = (float*)d_out;

    char* ws = (char*)d_ws;
    unsigned short* Wcatb = (unsigned short*)(ws + OFF_WCATB);
    float* bcat      = (float*)(ws + OFF_BCAT);
    unsigned short* xb = (unsigned short*)(ws + OFF_XB);
    unsigned* Cu     = (unsigned*)(ws + OFF_C);
    unsigned short* csr_src = (unsigned short*)(ws + OFF_SRC);
    unsigned* bucketed = (unsigned*)(ws + OFF_BKD);
    int*   cnt       = (int*)(ws + OFF_CNT);
    int*   bsum      = (int*)(ws + OFF_BSUM);
    int*   bktoff    = (int*)(ws + OFF_BOFF);
    int*   row_start = (int*)(ws + OFF_RS);
    float* agg       = (float*)(ws + OFF_AGG);

    const int* srcA = edge;
    const int* dstA = edge + N_EDGES;

    // D1: coarse bucket hist (LDS) || x->bf16 || weight prep
    k_prep<<<PREP_GRID, 256, 0, stream>>>(
        x, xb, Wq, bq, Wk, bk, Wv, bv, Wcatb, bcat, dstA, cnt);

    // D2: tiny scans -> per-(bucket,block) absolute offsets
    k_b2a<<<NBKT, 256, 0, stream>>>(cnt, bsum);
    k_b2b<<<1, 256, 0, stream>>>(bsum, bktoff);
    k_b2c<<<NBKT, 256, 0, stream>>>(cnt, bktoff);

    // D3: QKV MFMA GEMM || bucket scatter (LDS cursors)
    k_gemmqkv_b3<<<GB3_GRID, 256, 0, stream>>>(
        xb, Wcatb, bcat, Cu, N_NODES, srcA, dstA, cnt, bucketed);

    // D4: per-bucket fine counting sort -> csr_src + row_start
    k_b4<<<NBKT, 256, 0, stream>>>(bucketed, bktoff, csr_src, row_start);

    // D5: fused scores + softmax + V aggregate
    k_attn<<<(N_NODES + 3) / 4, 256, 0, stream>>>(Cu, row_start, csr_src, agg);

    // D6: out = relu(agg @ Wo^T + bo), MFMA bf16
    k_gemm<<<dim3((N_NODES + 63) / 64, 2), 256, 0, stream>>>(agg, Wo, bo, out, N_NODES);
}